// Round 6
// baseline (358.769 us; speedup 1.0000x reference)
//
#include <hip/hip_runtime.h>
#include <hip/hip_cooperative_groups.h>
#include <hip/hip_bf16.h>
#include <math.h>

#define NQ 4096
#define NK 4096
#define QD 256
#define KD 320
#define HID 256
#define NH 8
#define DH 32
#define NB 16
#define LN_EPS 1e-5f
#define ATT_SCALE 0.17677669529663687f   // 1/sqrt(32)

typedef unsigned short ushort_t;
typedef __attribute__((ext_vector_type(8))) short bf16x8_t;
typedef __attribute__((ext_vector_type(4))) short bf16x4_t;
typedef __attribute__((ext_vector_type(4))) float f32x4_t;
typedef __attribute__((ext_vector_type(8))) unsigned short ushortx8_t;

// ---------------------------------------------------------------------------
// ws layout (float offsets), ~19 MB
// ---------------------------------------------------------------------------
#define OFF_QNB   0         // bf16 [4096][256]
#define OFF_KNB   524288    // bf16 [4096][320]
#define OFF_Q2B   1179648   // bf16 [4096][256]
#define OFF_K2B   1703936
#define OFF_V2B   2228224
#define OFF_CTXB  2752512   // bf16 [4096][256]
#define OFF_XRES  3276800   // f32  [4096][256] (fallback path only)
#define OFF_WQB   4325376   // bf16 [256][256]
#define OFF_WKB   4358144   // bf16 [320][256]
#define OFF_WVB   4399104   // bf16 [320][256]
#define OFF_WINB  4440064   // bf16 [768][256]
#define OFF_MOWB  4538368   // bf16 [256][256]
#define OFF_WOTB  4571136   // bf16 [256][256]  Wo transposed: WoT[n][k]
#define OFF_WQT   4603904   // bf16 WeffQT [256][256]
#define OFF_WKT   4636672   // bf16 WeffKT [256][320]
#define OFF_WVT   4677632   // bf16 WeffVT [256][320]
#define OFF_WOT   4718592   // bf16 WeffOT [256][256]
#define OFF_BQ    4751360
#define OFF_BK    4751616
#define OFF_BV    4751872
#define OFF_BINP  4752128   // 768
#define OFF_MOB   4752896
#define OFF_BO    4753152
#define OFF_LNG   4753408
#define OFF_LNB   4753664
#define OFF_BEFFQ 4753920
#define OFF_BEFFK 4754176
#define OFF_BEFFV 4754432
#define OFF_BEFFO 4754688
#define OFF_KST   4754944   // 16 int
#define OFF_KEN   4754960   // 16 int
#define OFF_FLAG  4754976   // 1 int

__device__ __forceinline__ float bf16_bits_to_f(ushort_t s) {
    unsigned int u = (unsigned int)s << 16;
    float f;
    __builtin_memcpy(&f, &u, 4);
    return f;
}

__device__ __forceinline__ ushort_t f_to_bf16_bits(float v) {
    __hip_bfloat16 t = (__hip_bfloat16)v;
    ushort_t b;
    __builtin_memcpy(&b, &t, 2);
    return b;
}

// shared MFMA 64x64 tile: D[m][n] = sum_k A[m][k]*B[n][k]  (A·B^T form)
template <int K>
__device__ __forceinline__ void mm64(const ushort_t* __restrict__ Xrow,
                                     const ushort_t* __restrict__ Wrow,
                                     f32x4_t acc[4]) {
#pragma unroll
    for (int kc = 0; kc < K; kc += 32) {
        bf16x8_t af = *(const bf16x8_t*)(Xrow + kc);
#pragma unroll
        for (int t = 0; t < 4; ++t) {
            bf16x8_t bfrag = *(const bf16x8_t*)(Wrow + t * 16 * K + kc);
            acc[t] = __builtin_amdgcn_mfma_f32_16x16x32_bf16(af, bfrag, acc[t],
                                                             0, 0, 0);
        }
    }
}

struct KArgs {
    const void* in[18];
    float* ws;
    void* out;
};

// ===========================================================================
// ONE cooperative kernel: all phases separated by grid.sync().
// Grid-size agnostic (requires >= 76 blocks); 256 threads/block.
// ===========================================================================
__global__ __launch_bounds__(256, 2) void k_mega(KArgs a) {
    cooperative_groups::grid_group grid = cooperative_groups::this_grid();
    float* ws = a.ws;
    const int tid = threadIdx.x, bid = blockIdx.x;
    const int lane = tid & 63, wv = tid >> 6;
    const int col = lane & 15, quad = lane >> 4;
    const int gblocks = gridDim.x;
    const int gstride = gblocks * 256;

    __shared__ float s_red[4];
    __shared__ int s_flag;

    // ---- dtype flag (every block computes its own; no cross-block dep) ----
    {
        const ushort_t* probe = (const ushort_t*)a.in[0];
        float mx = 0.f;
        for (int i = tid; i < 4096; i += 256) {
            float f = fabsf(bf16_bits_to_f(probe[i]));
            if (!(f == f)) f = 1e38f;
            mx = fmaxf(mx, f);
        }
        for (int off = 32; off; off >>= 1)
            mx = fmaxf(mx, __shfl_xor(mx, off, 64));
        if (lane == 0) s_red[wv] = mx;
        __syncthreads();
        if (tid == 0) {
            float m2 = fmaxf(fmaxf(s_red[0], s_red[1]),
                             fmaxf(s_red[2], s_red[3]));
            s_flag = (m2 < 100.f) ? 1 : 0;
        }
        __syncthreads();
    }
    const int fl = s_flag;

    // =======================================================================
    // Phase A: batch ranges (blocks 0..15) + input conversion (grid-stride)
    // =======================================================================
    if (bid < 16) {
        const int* kb = (const int*)a.in[17];
        int* kstart = (int*)(ws + OFF_KST);
        int* kend   = (int*)(ws + OFF_KEN);
        int j = bid * 256 + tid;
        if (j < NK) {
            int b = kb[j];
            if (j == 0) {
                for (int x = 0; x < b; ++x) { kstart[x] = 0; kend[x] = 0; }
                kstart[b] = 0;
            } else {
                int bp = kb[j - 1];
                if (bp != b) {
                    kend[bp] = j;
                    for (int x = bp + 1; x < b; ++x) { kstart[x] = j; kend[x] = j; }
                    kstart[b] = j;
                }
            }
            if (j == NK - 1) {
                kend[b] = NK;
                for (int x = b + 1; x < NB; ++x) { kstart[x] = NK; kend[x] = NK; }
            }
        }
    }
    {
        // units of 8 elements; cumulative unit ends per segment
        const int uend[16] = {131072,294912,303104,303136,313376,313408,323648,
                              323680,348256,348352,356544,356576,364768,364800,
                              364832,364864};
        const int doff[16] = {OFF_QNB,OFF_KNB,OFF_WQB,OFF_BQ,OFF_WKB,OFF_BK,
                              OFF_WVB,OFF_BV,OFF_WINB,OFF_BINP,OFF_MOWB,
                              OFF_MOB,OFF_WOTB,OFF_BO,OFF_LNG,OFF_LNB};
        const int typ[16]  = {0,0,0,1,0,1,0,1,0,1,0,1,2,1,1,1};
        for (int u = bid * 256 + tid; u < 364864; u += gstride) {
            int s = 0;
            while (u >= uend[s]) ++s;
            int ubase = s ? uend[s - 1] : 0;
            int i0 = (u - ubase) * 8;
            const void* src = a.in[s];
            int ty = typ[s];
            if (ty == 1) {
                // f32 destination
                f32x4_t f0, f1;
                if (fl) {
                    ushortx8_t h = *(const ushortx8_t*)((const ushort_t*)src + i0);
#pragma unroll
                    for (int e = 0; e < 4; ++e) f0[e] = bf16_bits_to_f(h[e]);
#pragma unroll
                    for (int e = 0; e < 4; ++e) f1[e] = bf16_bits_to_f(h[4 + e]);
                } else {
                    f0 = *(const f32x4_t*)((const float*)src + i0);
                    f1 = *(const f32x4_t*)((const float*)src + i0 + 4);
                }
                float* d = ws + doff[s] + i0;
                *(f32x4_t*)d = f0;
                *(f32x4_t*)(d + 4) = f1;
            } else {
                ushort_t h8[8];
                if (fl) {
                    ushortx8_t h = *(const ushortx8_t*)((const ushort_t*)src + i0);
#pragma unroll
                    for (int e = 0; e < 8; ++e) h8[e] = h[e];
                } else {
                    f32x4_t f0 = *(const f32x4_t*)((const float*)src + i0);
                    f32x4_t f1 = *(const f32x4_t*)((const float*)src + i0 + 4);
#pragma unroll
                    for (int e = 0; e < 4; ++e) h8[e] = f_to_bf16_bits(f0[e]);
#pragma unroll
                    for (int e = 0; e < 4; ++e) h8[4 + e] = f_to_bf16_bits(f1[e]);
                }
                ushort_t* d = (ushort_t*)(ws + doff[s]);
                if (ty == 0) {
                    ushortx8_t hv;
#pragma unroll
                    for (int e = 0; e < 8; ++e) hv[e] = h8[e];
                    *(ushortx8_t*)(d + i0) = hv;
                } else {
                    // transpose Wo[k][n] -> WoT[n][k]
                    int k = i0 >> 8, n0 = i0 & 255;
#pragma unroll
                    for (int e = 0; e < 8; ++e) d[(n0 + e) * 256 + k] = h8[e];
                }
            }
        }
    }
    grid.sync();

    // =======================================================================
    // Phase B: weight fusion GEMMs (blocks 0..71) + effective biases (72..75)
    // =======================================================================
    if (bid < 72) {
        const ushort_t* winb = (const ushort_t*)(ws + OFF_WINB);
        const ushort_t *A, *B;
        ushort_t* Out;
        int N, mb, nb;
        int r = bid;
        if (r < 16)      { A = winb;          B = (const ushort_t*)(ws + OFF_WQB);  Out = (ushort_t*)(ws + OFF_WQT); N = 256; mb = r >> 2;  nb = r & 3; }
        else if (r < 36) { int rr = r - 16; A = winb + 65536;  B = (const ushort_t*)(ws + OFF_WKB);  Out = (ushort_t*)(ws + OFF_WKT); N = 320; mb = rr / 5; nb = rr % 5; }
        else if (r < 56) { int rr = r - 36; A = winb + 131072; B = (const ushort_t*)(ws + OFF_WVB);  Out = (ushort_t*)(ws + OFF_WVT); N = 320; mb = rr / 5; nb = rr % 5; }
        else             { int rr = r - 56; A = (const ushort_t*)(ws + OFF_WOTB); B = (const ushort_t*)(ws + OFF_MOWB); Out = (ushort_t*)(ws + OFF_WOT); N = 256; mb = rr >> 2; nb = rr & 3; }
        int m0 = mb * 64 + wv * 16, n0 = nb * 64;
        f32x4_t acc[4];
#pragma unroll
        for (int t = 0; t < 4; ++t) acc[t] = (f32x4_t){0.f, 0.f, 0.f, 0.f};
        mm64<256>(A + (size_t)(m0 + col) * 256 + quad * 8,
                  B + (size_t)(n0 + col) * 256 + quad * 8, acc);
#pragma unroll
        for (int t = 0; t < 4; ++t)
#pragma unroll
            for (int rr = 0; rr < 4; ++rr) {
                int m = m0 + quad * 4 + rr;
                int n = n0 + t * 16 + col;
                Out[(size_t)m * N + n] = f_to_bf16_bits(acc[t][rr]);
            }
    } else if (bid < 76) {
        int m = bid - 72, j = tid;
        const ushort_t* winb = (const ushort_t*)(ws + OFF_WINB);
        const ushort_t* wotb = (const ushort_t*)(ws + OFF_WOTB);
        float acc = 0.f;
        if (m < 3) {
            const float* b = (m == 0) ? (ws + OFF_BQ) : (m == 1) ? (ws + OFF_BK)
                                                                 : (ws + OFF_BV);
            const ushort_t* wrow = winb + (size_t)(m * 256 + j) * 256;
            for (int k = 0; k < 256; ++k) acc += b[k] * bf16_bits_to_f(wrow[k]);
            acc += (ws + OFF_BINP)[m * 256 + j];
            float* o = (m == 0) ? (ws + OFF_BEFFQ) : (m == 1) ? (ws + OFF_BEFFK)
                                                              : (ws + OFF_BEFFV);
            o[j] = acc;
        } else {
            const float* mob = ws + OFF_MOB;
            const ushort_t* wrow = wotb + (size_t)j * 256;
            for (int k = 0; k < 256; ++k) acc += mob[k] * bf16_bits_to_f(wrow[k]);
            acc += (ws + OFF_BO)[j];
            (ws + OFF_BEFFO)[j] = acc;
        }
    }
    grid.sync();

    // =======================================================================
    // Phase C: Q/K/V projections. 768 units of (64-row x 64-col) tiles.
    //   u<256: Q (K=256); u<512: Kproj (K=320); else V (K=320)
    // =======================================================================
    for (int u = bid; u < 768; u += gblocks) {
        const ushort_t* X;
        const ushort_t* WT;
        const float* bias;
        ushort_t* Z;
        int mt, nt, KK;
        if (u < 256) {
            X = (const ushort_t*)(ws + OFF_QNB); WT = (const ushort_t*)(ws + OFF_WQT);
            bias = ws + OFF_BEFFQ; Z = (ushort_t*)(ws + OFF_Q2B);
            mt = u >> 2; nt = u & 3; KK = 256;
        } else if (u < 512) {
            int uu = u - 256;
            X = (const ushort_t*)(ws + OFF_KNB); WT = (const ushort_t*)(ws + OFF_WKT);
            bias = ws + OFF_BEFFK; Z = (ushort_t*)(ws + OFF_K2B);
            mt = uu >> 2; nt = uu & 3; KK = 320;
        } else {
            int uu = u - 512;
            X = (const ushort_t*)(ws + OFF_KNB); WT = (const ushort_t*)(ws + OFF_WVT);
            bias = ws + OFF_BEFFV; Z = (ushort_t*)(ws + OFF_V2B);
            mt = uu >> 2; nt = uu & 3; KK = 320;
        }
        int m0 = mt * 64 + wv * 16, n0 = nt * 64;
        f32x4_t acc[4];
#pragma unroll
        for (int t = 0; t < 4; ++t) acc[t] = (f32x4_t){0.f, 0.f, 0.f, 0.f};
        if (KK == 256)
            mm64<256>(X + (size_t)(m0 + col) * 256 + quad * 8,
                      WT + (size_t)(n0 + col) * 256 + quad * 8, acc);
        else
            mm64<320>(X + (size_t)(m0 + col) * 320 + quad * 8,
                      WT + (size_t)(n0 + col) * 320 + quad * 8, acc);
#pragma unroll
        for (int t = 0; t < 4; ++t)
#pragma unroll
            for (int rr = 0; rr < 4; ++rr) {
                int m = m0 + quad * 4 + rr;
                int n = n0 + t * 16 + col;
                Z[(size_t)m * 256 + n] = f_to_bf16_bits(acc[t][rr] + bias[n]);
            }
    }
    grid.sync();

    // =======================================================================
    // Phase D: MFMA flash attention. 512 units: (16-query tile, 4-head group)
    // =======================================================================
    for (int u = bid; u < 512; u += gblocks) {
        const ushort_t* q2b = (const ushort_t*)(ws + OFF_Q2B);
        const ushort_t* k2b = (const ushort_t*)(ws + OFF_K2B);
        const ushort_t* v2b = (const ushort_t*)(ws + OFF_V2B);
        const int* qb  = (const int*)a.in[16];
        const int* kst = (const int*)(ws + OFF_KST);
        const int* ken = (const int*)(ws + OFF_KEN);
        ushort_t* ctxb = (ushort_t*)(ws + OFF_CTXB);

        int qt = u >> 1;
        int h  = ((u & 1) << 2) | wv;
        int q0 = qt * 16;

        int qq = q0 + col;
        int bq_ = qb[qq];
        int j0q = kst[bq_], j1q = ken[bq_];
        int jlo = j0q, jhi = j1q;
#pragma unroll
        for (int off = 1; off < 16; off <<= 1) {
            jlo = min(jlo, __shfl_xor(jlo, off, 64));
            jhi = max(jhi, __shfl_xor(jhi, off, 64));
        }

        bf16x8_t qf = *(const bf16x8_t*)(q2b + (size_t)qq * HID + h * DH + quad * 8);

        f32x4_t accO = {0.f, 0.f, 0.f, 0.f};
        float m_st = -1e30f, l_st = 0.f;

        for (int kt = jlo; kt < jhi; kt += 16) {
            int krow = kt + col;
            if (krow > NK - 1) krow = NK - 1;
            bf16x8_t kf = *(const bf16x8_t*)(k2b + (size_t)krow * HID + h * DH + quad * 8);
            ushort_t vr[4];
#pragma unroll
            for (int j = 0; j < 4; ++j) {
                int vrow = kt + quad * 4 + j;
                if (vrow > NK - 1) vrow = NK - 1;
                vr[j] = v2b[(size_t)vrow * HID + h * DH + col];
            }
            f32x4_t S = __builtin_amdgcn_mfma_f32_16x16x32_bf16(
                kf, qf, (f32x4_t){0.f, 0.f, 0.f, 0.f}, 0, 0, 0);

            float s[4];
            float mt = -3e38f;
#pragma unroll
            for (int r = 0; r < 4; ++r) {
                int kk = kt + quad * 4 + r;
                bool ok = (kk >= j0q) && (kk < j1q);
                s[r] = ok ? S[r] * ATT_SCALE : -3e38f;
                mt = fmaxf(mt, s[r]);
            }
            mt = fmaxf(mt, __shfl_xor(mt, 16, 64));
            mt = fmaxf(mt, __shfl_xor(mt, 32, 64));
            float m_new = fmaxf(m_st, mt);
            float alpha = __expf(m_st - m_new);
            float p[4], ps = 0.f;
#pragma unroll
            for (int r = 0; r < 4; ++r) { p[r] = __expf(s[r] - m_new); ps += p[r]; }
            ps += __shfl_xor(ps, 16, 64);
            ps += __shfl_xor(ps, 32, 64);
            l_st = l_st * alpha + ps;
            m_st = m_new;

            bf16x4_t pb, vb;
#pragma unroll
            for (int r = 0; r < 4; ++r) {
                pb[r] = (short)f_to_bf16_bits(p[r]);
                vb[r] = (short)vr[r];
            }
#pragma unroll
            for (int r = 0; r < 4; ++r) {
                float aq = __shfl(alpha, quad * 4 + r, 64);
                accO[r] *= aq;
            }
            accO = __builtin_amdgcn_mfma_f32_16x16x16bf16_1k(pb, vb, accO, 0, 0, 0);
        }

#pragma unroll
        for (int r = 0; r < 4; ++r) {
            float lq = __shfl(l_st, quad * 4 + r, 64);
            float o = (lq > 0.f) ? accO[r] / lq : 0.f;
            int qrow = q0 + quad * 4 + r;
            ctxb[(size_t)qrow * HID + h * DH + col] = f_to_bf16_bits(o);
        }
    }
    grid.sync();

    // =======================================================================
    // Phase E: O-projection + residual + LayerNorm fused. 64 units of 64 rows;
    // each wave: 16 rows x 256 cols (16 MFMA tiles), LN in-wave.
    // =======================================================================
    for (int u = bid; u < 64; u += gblocks) {
        const ushort_t* ctxb = (const ushort_t*)(ws + OFF_CTXB);
        const ushort_t* wot  = (const ushort_t*)(ws + OFF_WOT);
        const ushort_t* qnb  = (const ushort_t*)(ws + OFF_QNB);
        const float* beffO = ws + OFF_BEFFO;
        const float* lng = ws + OFF_LNG;
        const float* lnb = ws + OFF_LNB;

        int m0 = u * 64 + wv * 16;
        f32x4_t acc[16];
#pragma unroll
        for (int t = 0; t < 16; ++t) acc[t] = (f32x4_t){0.f, 0.f, 0.f, 0.f};
        const ushort_t* Xrow = ctxb + (size_t)(m0 + col) * 256 + quad * 8;
        const ushort_t* Wbase = wot + (size_t)col * 256 + quad * 8;
#pragma unroll
        for (int kc = 0; kc < 256; kc += 32) {
            bf16x8_t af = *(const bf16x8_t*)(Xrow + kc);
#pragma unroll
            for (int t = 0; t < 16; ++t) {
                bf16x8_t bfrag = *(const bf16x8_t*)(Wbase + (size_t)t * 16 * 256 + kc);
                acc[t] = __builtin_amdgcn_mfma_f32_16x16x32_bf16(af, bfrag,
                                                                 acc[t], 0, 0, 0);
            }
        }
        // x = proj + bias + residual; accumulate row stats
        float s_[4] = {0.f, 0.f, 0.f, 0.f};
        float ss_[4] = {0.f, 0.f, 0.f, 0.f};
#pragma unroll
        for (int t = 0; t < 16; ++t) {
            int n = t * 16 + col;
            float b = beffO[n];
#pragma unroll
            for (int rr = 0; rr < 4; ++rr) {
                int m = m0 + quad * 4 + rr;
                float x = acc[t][rr] + b +
                          bf16_bits_to_f(qnb[(size_t)m * 256 + n]);
                acc[t][rr] = x;
                s_[rr] += x;
                ss_[rr] += x * x;
            }
        }
#pragma unroll
        for (int off = 1; off < 16; off <<= 1) {
#pragma unroll
            for (int rr = 0; rr < 4; ++rr) {
                s_[rr]  += __shfl_xor(s_[rr],  off, 16);
                ss_[rr] += __shfl_xor(ss_[rr], off, 16);
            }
        }
        float mu[4], inv[4];
#pragma unroll
        for (int rr = 0; rr < 4; ++rr) {
            mu[rr] = s_[rr] * (1.f / QD);
            float var = ss_[rr] * (1.f / QD) - mu[rr] * mu[rr];
            inv[rr] = rsqrtf(var + LN_EPS);
        }
#pragma unroll
        for (int t = 0; t < 16; ++t) {
            int n = t * 16 + col;
            float g = lng[n], bb = lnb[n];
#pragma unroll
            for (int rr = 0; rr < 4; ++rr) {
                int m = m0 + quad * 4 + rr;
                float y = (acc[t][rr] - mu[rr]) * inv[rr] * g + bb;
                size_t idx = (size_t)m * 256 + n;
                if (fl) ((ushort_t*)a.out)[idx] = f_to_bf16_bits(y);
                else    ((float*)a.out)[idx] = y;
            }
        }
    }
}

// ===========================================================================
// FALLBACK PATH (round-5 kernel chain), used only if cooperative launch fails
// ===========================================================================
__global__ void k_detect(const ushort_t* __restrict__ probe,
                         int* __restrict__ flag) {
    __shared__ float red[4];
    int t = threadIdx.x;
    float mx = 0.f;
    for (int i = t; i < 4096; i += 256) {
        float f = fabsf(bf16_bits_to_f(probe[i]));
        if (!(f == f)) f = 1e38f;
        mx = fmaxf(mx, f);
    }
    for (int off = 32; off; off >>= 1) mx = fmaxf(mx, __shfl_xor(mx, off, 64));
    if ((t & 63) == 0) red[t >> 6] = mx;
    __syncthreads();
    if (t == 0) {
        mx = fmaxf(fmaxf(red[0], red[1]), fmaxf(red[2], red[3]));
        *flag = (mx < 100.f) ? 1 : 0;
    }
}

struct Ptrs16 { const void* p[16]; };
#define CVT_TOTAL 2918912

__global__ void k_cvt_all(Ptrs16 ps, float* __restrict__ ws,
                          const int* __restrict__ flag) {
    const int ns[16]   = {1048576,1310720,65536,256,81920,256,81920,256,
                          196608,768,65536,256,65536,256,256,256};
    const int doff[16] = {OFF_QNB,OFF_KNB,OFF_WQB,OFF_BQ,OFF_WKB,OFF_BK,
                          OFF_WVB,OFF_BV,OFF_WINB,OFF_BINP,OFF_MOWB,
                          OFF_MOB,OFF_WOTB,OFF_BO,OFF_LNG,OFF_LNB};
    const int typ[16]  = {0,0,0,1,0,1,0,1,0,1,0,1,2,1,1,1};
    int gid = blockIdx.x * 256 + threadIdx.x;
    if (gid >= CVT_TOTAL) return;
    int fl = *flag;
    int base = 0;
#pragma unroll
    for (int s = 0; s < 16; ++s) {
        int n = ns[s];
        if (gid < base + n) {
            int i = gid - base;
            if (typ[s] == 1) {
                float v = fl ? bf16_bits_to_f(((const ushort_t*)ps.p[s])[i])
                             : ((const float*)ps.p[s])[i];
                ws[doff[s] + i] = v;
            } else {
                ushort_t h = fl ? ((const ushort_t*)ps.p[s])[i]
                                : f_to_bf16_bits(((const float*)ps.p[s])[i]);
                ushort_t* d = (ushort_t*)(ws + doff[s]);
                int di = (typ[s] == 2) ? ((i & 255) * 256 + (i >> 8)) : i;
                d[di] = h;
            }
            return;
        }
        base += n;
    }
}

__global__ void k_ranges(const int* __restrict__ kb, int* __restrict__ kstart,
                         int* __restrict__ kend) {
    int j = blockIdx.x * 256 + threadIdx.x;
    if (j >= NK) return;
    int b = kb[j];
    if (j == 0) {
        for (int x = 0; x < b; ++x) { kstart[x] = 0; kend[x] = 0; }
        kstart[b] = 0;
    } else {
        int bp = kb[j - 1];
        if (bp != b) {
            kend[bp] = j;
            for (int x = bp + 1; x < b; ++x) { kstart[x] = j; kend[x] = j; }
            kstart[b] = j;
        }
    }
    if (j == NK - 1) {
        kend[b] = NK;
        for (int x = b + 1; x < NB; ++x) { kstart[x] = NK; kend[x] = NK; }
    }
}

__global__ __launch_bounds__(256) void k_fuse_gemm(
        const ushort_t* __restrict__ winb, const ushort_t* __restrict__ wqb,
        const ushort_t* __restrict__ wkb, const ushort_t* __restrict__ wvb,
        const ushort_t* __restrict__ wotb, const ushort_t* __restrict__ mowb,
        ushort_t* __restrict__ wqt, ushort_t* __restrict__ wkt,
        ushort_t* __restrict__ wvt, ushort_t* __restrict__ wot) {
    int r = blockIdx.x;
    const ushort_t *A, *B;
    ushort_t* Out;
    int N, mb, nb;
    if (r < 16)      { A = winb;          B = wqb;  Out = wqt; N = 256; mb = r >> 2;  nb = r & 3; }
    else if (r < 36) { int rr = r - 16; A = winb + 65536;  B = wkb;  Out = wkt; N = 320; mb = rr / 5; nb = rr % 5; }
    else if (r < 56) { int rr = r - 36; A = winb + 131072; B = wvb;  Out = wvt; N = 320; mb = rr / 5; nb = rr % 5; }
    else             { int rr = r - 56; A = wotb;          B = mowb; Out = wot; N = 256; mb = rr >> 2; nb = rr & 3; }
    int w = threadIdx.x >> 6, lane = threadIdx.x & 63;
    int col = lane & 15, quad = lane >> 4;
    int m0 = mb * 64 + w * 16, n0 = nb * 64;
    f32x4_t acc[4];
#pragma unroll
    for (int t = 0; t < 4; ++t) acc[t] = (f32x4_t){0.f, 0.f, 0.f, 0.f};
    mm64<256>(A + (size_t)(m0 + col) * 256 + quad * 8,
              B + (size_t)(n0 + col) * 256 + quad * 8, acc);
#pragma unroll
    for (int t = 0; t < 4; ++t)
#pragma unroll
        for (int rr = 0; rr < 4; ++rr) {
            int m = m0 + quad * 4 + rr;
            int n = n0 + t * 16 + col;
            Out[(size_t)m * N + n] = f_to_bf16_bits(acc[t][rr]);
        }
}

__global__ void k_bias(const float* __restrict__ bq, const float* __restrict__ bk,
                       const float* __restrict__ bv, const float* __restrict__ binp,
                       const float* __restrict__ mob, const float* __restrict__ bo,
                       const ushort_t* __restrict__ winb,
                       const ushort_t* __restrict__ wotb,
                       float* __restrict__ beffQ, float* __restrict__ beffK,
                       float* __restrict__ beffV, float* __restrict__ beffO) {
    int m = blockIdx.x, j = threadIdx.x;
    float acc = 0.f;
    if (m < 3) {
        const float* b = (m == 0) ? bq : (m == 1) ? bk : bv;
        const ushort_t* wrow = winb + (size_t)(m * 256 + j) * 256;
        for (int k = 0; k < 256; ++k) acc += b[k] * bf16_bits_to_f(wrow[k]);
        acc += binp[m * 256 + j];
        float* o = (m == 0) ? beffQ : (m == 1) ? beffK : beffV;
        o[j] = acc;
    } else {
        const ushort_t* wrow = wotb + (size_t)j * 256;
        for (int k = 0; k < 256; ++k) acc += mob[k] * bf16_bits_to_f(wrow[k]);
        acc += bo[j];
        beffO[j] = acc;
    }
}

template <int K, int OUTBF, int RES>
__global__ __launch_bounds__(256) void k_gemm(
        const ushort_t* __restrict__ X,
        const ushort_t* __restrict__ WT0, const ushort_t* __restrict__ WT1,
        const float* __restrict__ b0, const float* __restrict__ b1,
        void* __restrict__ Z0, void* __restrict__ Z1,
        const ushort_t* __restrict__ res) {
    const ushort_t* WT = blockIdx.z ? WT1 : WT0;
    const float* bias  = blockIdx.z ? b1 : b0;
    void* Z            = blockIdx.z ? Z1 : Z0;
    int w = threadIdx.x >> 6, lane = threadIdx.x & 63;
    int col = lane & 15, quad = lane >> 4;
    int m0 = blockIdx.x * 64 + w * 16, n0 = blockIdx.y * 64;
    f32x4_t acc[4];
#pragma unroll
    for (int t = 0; t < 4; ++t) acc[t] = (f32x4_t){0.f, 0.f, 0.f, 0.f};
    mm64<K>(X + (size_t)(m0 + col) * K + quad * 8,
            WT + (size_t)(n0 + col) * K + quad * 8, acc);
#pragma unroll
    for (int t = 0; t < 4; ++t)
#pragma unroll
        for (int rr = 0; rr < 4; ++rr) {
            int m = m0 + quad * 4 + rr;
            int n = n0 + t * 16 + col;
            float v = acc[t][rr] + bias[n];
            if (RES) v += bf16_bits_to_f(res[(size_t)m * 256 + n]);
            size_t idx = (size_t)m * 256 + n;
            if (OUTBF) ((ushort_t*)Z)[idx] = f_to_bf16_bits(v);
            else       ((float*)Z)[idx] = v;
        }
}

__global__ __launch_bounds__(256) void k_attn_mfma(
        const ushort_t* __restrict__ q2b, const ushort_t* __restrict__ k2b,
        const ushort_t* __restrict__ v2b, const int* __restrict__ qb,
        const int* __restrict__ kst, const int* __restrict__ ken,
        ushort_t* __restrict__ ctxb) {
    int wave = threadIdx.x >> 6;
    int lane = threadIdx.x & 63;
    int qt = blockIdx.x >> 1;
    int h  = ((blockIdx.x & 1) << 2) | wave;
    int q0 = qt * 16;
    int col  = lane & 15;
    int quad = lane >> 4;

    int qq = q0 + col;
    int bq_ = qb[qq];
    int j0q = kst[bq_], j1q = ken[bq_];
    int jlo = j0q, jhi = j1q;
#pragma unroll
    for (int off = 1; off < 16; off <<= 1) {
        jlo = min(jlo, __shfl_xor(jlo, off, 64));
        jhi = max(jhi, __shfl_xor(jhi, off, 64));
    }

    bf16x8_t qf = *(const bf16x8_t*)(q2b + (size_t)qq * HID + h * DH + quad * 8);

    f32x4_t accO = {0.f, 0.f, 0.f, 0.f};
    float m_st = -1e30f, l_st = 0.f;

    for (int kt = jlo; kt < jhi; kt += 16) {
        int krow = kt + col;
        if (krow > NK - 1) krow = NK - 1;
        bf16x8_t kf = *(const bf16x8_t*)(k2b + (size_t)krow * HID + h * DH + quad * 8);
        ushort_t vr[4];
#pragma unroll
        for (int j = 0; j < 4; ++j) {
            int vrow = kt + quad * 4 + j;
            if (vrow > NK - 1) vrow = NK - 1;
            vr[j] = v2b[(size_t)vrow * HID + h * DH + col];
        }
        f32x4_t S = __builtin_amdgcn_mfma_f32_16x16x32_bf16(
            kf, qf, (f32x4_t){0.f, 0.f, 0.f, 0.f}, 0, 0, 0);

        float s[4];
        float mt = -3e38f;
#pragma unroll
        for (int r = 0; r < 4; ++r) {
            int kk = kt + quad * 4 + r;
            bool ok = (kk >= j0q) && (kk < j1q);
            s[r] = ok ? S[r] * ATT_SCALE : -3e38f;
            mt = fmaxf(mt, s[r]);
        }
        mt = fmaxf(mt, __shfl_xor(mt, 16, 64));
        mt = fmaxf(mt, __shfl_xor(mt, 32, 64));
        float m_new = fmaxf(m_st, mt);
        float alpha = __expf(m_st - m_new);
        float p[4], ps = 0.f;
#pragma unroll
        for (int r = 0; r < 4; ++r) { p[r] = __expf(s[r] - m_new); ps += p[r]; }
        ps += __shfl_xor(ps, 16, 64);
        ps += __shfl_xor(ps, 32, 64);
        l_st = l_st * alpha + ps;
        m_st = m_new;

        bf16x4_t pb, vb;
#pragma unroll
        for (int r = 0; r < 4; ++r) {
            pb[r] = (short)f_to_bf16_bits(p[r]);
            vb[r] = (short)vr[r];
        }
#pragma unroll
        for (int r = 0; r < 4; ++r) {
            float aq = __shfl(alpha, quad * 4 + r, 64);
            accO[r] *= aq;
        }
        accO = __builtin_amdgcn_mfma_f32_16x16x16bf16_1k(pb, vb, accO, 0, 0, 0);
    }

#pragma unroll
    for (int r = 0; r < 4; ++r) {
        float lq = __shfl(l_st, quad * 4 + r, 64);
        float o = (lq > 0.f) ? accO[r] / lq : 0.f;
        int qrow = q0 + quad * 4 + r;
        ctxb[(size_t)qrow * HID + h * DH + col] = f_to_bf16_bits(o);
    }
}

__global__ void k_ln(const float* __restrict__ X, const float* __restrict__ g,
                     const float* __restrict__ bb, void* __restrict__ out,
                     const int* __restrict__ flag) {
    __shared__ float red[8];
    int q = blockIdx.x, t = threadIdx.x;
    float x = X[(size_t)q * QD + t];
    float s = x, ss = x * x;
    for (int off = 32; off; off >>= 1) {
        s += __shfl_xor(s, off, 64);
        ss += __shfl_xor(ss, off, 64);
    }
    int w = t >> 6;
    if ((t & 63) == 0) { red[w] = s; red[4 + w] = ss; }
    __syncthreads();
    s = red[0] + red[1] + red[2] + red[3];
    ss = red[4] + red[5] + red[6] + red[7];
    float mu = s * (1.f / QD);
    float var = ss * (1.f / QD) - mu * mu;
    float inv = rsqrtf(var + LN_EPS);
    float y = (x - mu) * inv * g[t] + bb[t];
    size_t idx = (size_t)q * QD + t;
    if (*flag)
        ((__hip_bfloat16*)out)[idx] = (__hip_bfloat16)y;
    else
        ((float*)out)[idx] = y;
}

extern "C" void kernel_launch(void* const* d_in, const int* in_sizes, int n_in,
                              void* d_out, int out_size, void* d_ws, size_t ws_size,
                              hipStream_t stream) {
    float* w = (float*)d_ws;

    KArgs a;
    for (int i = 0; i < 18; ++i) a.in[i] = d_in[i];
    a.ws = w;
    a.out = d_out;

    // grid sized for guaranteed co-residency (launch_bounds(256,2) => >=2/CU)
    int nb = 0;
    hipError_t oe = hipOccupancyMaxActiveBlocksPerMultiprocessor(
        &nb, (const void*)k_mega, 256, 0);
    int grid = 512;
    if (oe == hipSuccess && nb > 0) {
        int maxg = nb * 256;  // 256 CUs
        if (maxg < grid) grid = maxg;
    }
    if (grid < 76) grid = 76;  // phase B needs 76 blocks

    void* params[1] = {&a};
    hipError_t e = hipLaunchCooperativeKernel((const void*)k_mega, dim3(grid),
                                              dim3(256), params, 0, stream);
    if (e == hipSuccess) return;

    // ---------------- fallback: round-5 multi-kernel chain ----------------
    const int* qbi = (const int*)d_in[16];
    const int* kbi = (const int*)d_in[17];
    ushort_t* qnb  = (ushort_t*)(w + OFF_QNB);
    ushort_t* knb  = (ushort_t*)(w + OFF_KNB);
    ushort_t* q2b  = (ushort_t*)(w + OFF_Q2B);
    ushort_t* k2b  = (ushort_t*)(w + OFF_K2B);
    ushort_t* v2b  = (ushort_t*)(w + OFF_V2B);
    ushort_t* ctxb = (ushort_t*)(w + OFF_CTXB);
    float*    xres = w + OFF_XRES;
    ushort_t* wqb  = (ushort_t*)(w + OFF_WQB);
    ushort_t* wkb  = (ushort_t*)(w + OFF_WKB);
    ushort_t* wvb  = (ushort_t*)(w + OFF_WVB);
    ushort_t* winb = (ushort_t*)(w + OFF_WINB);
    ushort_t* mowb = (ushort_t*)(w + OFF_MOWB);
    ushort_t* wotb = (ushort_t*)(w + OFF_WOTB);
    ushort_t* wqt  = (ushort_t*)(w + OFF_WQT);
    ushort_t* wkt  = (ushort_t*)(w + OFF_WKT);
    ushort_t* wvt  = (ushort_t*)(w + OFF_WVT);
    ushort_t* wot  = (ushort_t*)(w + OFF_WOT);
    int* kst  = (int*)(w + OFF_KST);
    int* ken  = (int*)(w + OFF_KEN);
    int* flag = (int*)(w + OFF_FLAG);

    Ptrs16 ps;
    for (int i = 0; i < 16; ++i) ps.p[i] = d_in[i];

    k_detect<<<1, 256, 0, stream>>>((const ushort_t*)d_in[0], flag);
    k_cvt_all<<<(CVT_TOTAL + 255) / 256, 256, 0, stream>>>(ps, w, flag);
    k_ranges<<<NK / 256, 256, 0, stream>>>(kbi, kst, ken);
    k_fuse_gemm<<<72, 256, 0, stream>>>(winb, wqb, wkb, wvb, wotb, mowb,
                                        wqt, wkt, wvt, wot);
    k_bias<<<4, 256, 0, stream>>>(w + OFF_BQ, w + OFF_BK, w + OFF_BV,
                                  w + OFF_BINP, w + OFF_MOB, w + OFF_BO,
                                  winb, wotb, w + OFF_BEFFQ, w + OFF_BEFFK,
                                  w + OFF_BEFFV, w + OFF_BEFFO);
    k_gemm<256, 1, 0><<<dim3(NQ / 64, 4, 1), 256, 0, stream>>>(
        qnb, wqt, wqt, w + OFF_BEFFQ, w + OFF_BEFFQ, q2b, q2b, nullptr);
    k_gemm<320, 1, 0><<<dim3(NK / 64, 4, 2), 256, 0, stream>>>(
        knb, wkt, wvt, w + OFF_BEFFK, w + OFF_BEFFV, k2b, v2b, nullptr);
    k_attn_mfma<<<(NQ / 16) * 2, 256, 0, stream>>>(q2b, k2b, v2b, qbi, kst, ken,
                                                   ctxb);
    k_gemm<256, 0, 1><<<dim3(NQ / 64, 4, 1), 256, 0, stream>>>(
        ctxb, wot, wot, w + OFF_BEFFO, w + OFF_BEFFO, xres, xres, qnb);
    k_ln<<<NQ, 256, 0, stream>>>(xres, w + OFF_LNG, w + OFF_LNB, d_out, flag);
}

// Round 7
// 166.754 us; speedup vs baseline: 2.1515x; 2.1515x over previous
//
#include <hip/hip_runtime.h>
#include <hip/hip_bf16.h>
#include <math.h>

#define NQ 4096
#define NK 4096
#define QD 256
#define KD 320
#define HID 256
#define NH 8
#define DH 32
#define NB 16
#define LN_EPS 1e-5f
#define ATT_SCALE 0.17677669529663687f   // 1/sqrt(32)

typedef unsigned short ushort_t;
typedef __attribute__((ext_vector_type(8))) short bf16x8_t;
typedef __attribute__((ext_vector_type(4))) short bf16x4_t;
typedef __attribute__((ext_vector_type(4))) float f32x4_t;
typedef __attribute__((ext_vector_type(8))) unsigned short ushortx8_t;

// ---------------------------------------------------------------------------
// ws layout (float offsets), ~9 MB. No input staging — kernels read d_in
// directly with inline dtype conversion.
// ---------------------------------------------------------------------------
#define OFF_Q2B   0         // bf16 [4096][256]
#define OFF_K2B   524288    // bf16 [4096][256]
#define OFF_V2B   1048576   // bf16 [4096][256]
#define OFF_CTXB  1572864   // bf16 [4096][256]
#define OFF_WQT   2097152   // bf16 WeffQT [256][256]
#define OFF_WKT   2129920   // bf16 WeffKT [256][320]
#define OFF_WVT   2170880   // bf16 WeffVT [256][320]
#define OFF_WOT   2211840   // bf16 WeffOT [256][256]
#define OFF_BEFF  2244608   // f32 [4][256]: Q,K,V,O
#define OFF_KST   2245632   // 16 int
#define OFF_KEN   2245648   // 16 int
#define OFF_FLAG  2245664   // 1 int

struct KArgs {
    const void* in[18];
    float* ws;
    void* out;
};

__device__ __forceinline__ float bf16_bits_to_f(ushort_t s) {
    unsigned int u = (unsigned int)s << 16;
    float f;
    __builtin_memcpy(&f, &u, 4);
    return f;
}

__device__ __forceinline__ ushort_t f_to_bf16_bits(float v) {
    __hip_bfloat16 t = (__hip_bfloat16)v;
    ushort_t b;
    __builtin_memcpy(&b, &t, 2);
    return b;
}

// dtype-generic loaders: F32=false -> input is bf16; F32=true -> input is f32
template <bool F32>
__device__ __forceinline__ bf16x8_t ld8(const void* p, size_t idx) {
    if constexpr (!F32) {
        return *(const bf16x8_t*)((const ushort_t*)p + idx);
    } else {
        f32x4_t f0 = *(const f32x4_t*)((const float*)p + idx);
        f32x4_t f1 = *(const f32x4_t*)((const float*)p + idx + 4);
        bf16x8_t h;
#pragma unroll
        for (int e = 0; e < 4; ++e) h[e] = (short)f_to_bf16_bits(f0[e]);
#pragma unroll
        for (int e = 0; e < 4; ++e) h[4 + e] = (short)f_to_bf16_bits(f1[e]);
        return h;
    }
}

template <bool F32>
__device__ __forceinline__ float ld1f(const void* p, size_t idx) {
    if constexpr (F32) return ((const float*)p)[idx];
    else               return bf16_bits_to_f(((const ushort_t*)p)[idx]);
}

template <bool F32>
__device__ __forceinline__ ushort_t ld1h(const void* p, size_t idx) {
    if constexpr (F32) return f_to_bf16_bits(((const float*)p)[idx]);
    else               return ((const ushort_t*)p)[idx];
}

// per-block dtype probe on first 8KB of query_nodes (in-bounds either way)
__device__ __forceinline__ int detect_flag(const void* probe_v, int tid) {
    __shared__ float s_red[4];
    const ushort_t* probe = (const ushort_t*)probe_v;
    float mx = 0.f;
    for (int i = tid; i < 4096; i += 256) {
        float f = fabsf(bf16_bits_to_f(probe[i]));
        if (!(f == f)) f = 1e38f;
        mx = fmaxf(mx, f);
    }
    for (int off = 32; off; off >>= 1) mx = fmaxf(mx, __shfl_xor(mx, off, 64));
    if ((tid & 63) == 0) s_red[tid >> 6] = mx;
    __syncthreads();
    float m2 = fmaxf(fmaxf(s_red[0], s_red[1]), fmaxf(s_red[2], s_red[3]));
    return (m2 < 100.f) ? 1 : 0;
}

// ---------------------------------------------------------------------------
// K1: ranges (blocks 0..15) + weight-fusion GEMMs (16..87) + biases (88..91)
// ---------------------------------------------------------------------------
template <bool F32>
__device__ __forceinline__ void fuse_qkv_tile(const void* A, size_t abase,
                                              const void* B, ushort_t* Out,
                                              int N, int m0, int n0,
                                              int col, int quad) {
    f32x4_t acc[4];
#pragma unroll
    for (int t = 0; t < 4; ++t) acc[t] = (f32x4_t){0.f, 0.f, 0.f, 0.f};
    size_t aoff = abase + (size_t)(m0 + col) * 256 + quad * 8;
    size_t boff = (size_t)(n0 + col) * 256 + quad * 8;
#pragma unroll
    for (int kc = 0; kc < 256; kc += 32) {
        bf16x8_t af = ld8<F32>(A, aoff + kc);
#pragma unroll
        for (int t = 0; t < 4; ++t) {
            bf16x8_t bf = ld8<F32>(B, boff + (size_t)t * 16 * 256 + kc);
            acc[t] = __builtin_amdgcn_mfma_f32_16x16x32_bf16(af, bf, acc[t], 0, 0, 0);
        }
    }
#pragma unroll
    for (int t = 0; t < 4; ++t)
#pragma unroll
        for (int rr = 0; rr < 4; ++rr)
            Out[(size_t)(m0 + quad * 4 + rr) * N + n0 + t * 16 + col] =
                f_to_bf16_bits(acc[t][rr]);
}

// WeffOT[n][k'] = sum_j Wo[j][n] * mow[k'][j]  (A-frag gathered from Wo cols)
template <bool F32>
__device__ __forceinline__ void fuse_o_tile(const void* Wo, const void* Mow,
                                            ushort_t* Out, int m0, int n0,
                                            int col, int quad) {
    f32x4_t acc[4];
#pragma unroll
    for (int t = 0; t < 4; ++t) acc[t] = (f32x4_t){0.f, 0.f, 0.f, 0.f};
#pragma unroll
    for (int kc = 0; kc < 256; kc += 32) {
        bf16x8_t af;
#pragma unroll
        for (int t = 0; t < 8; ++t)
            af[t] = (short)ld1h<F32>(Wo, (size_t)(kc + quad * 8 + t) * 256 + m0 + col);
#pragma unroll
        for (int t = 0; t < 4; ++t) {
            bf16x8_t bf = ld8<F32>(Mow, (size_t)(n0 + t * 16 + col) * 256 + quad * 8 + kc);
            acc[t] = __builtin_amdgcn_mfma_f32_16x16x32_bf16(af, bf, acc[t], 0, 0, 0);
        }
    }
#pragma unroll
    for (int t = 0; t < 4; ++t)
#pragma unroll
        for (int rr = 0; rr < 4; ++rr)
            Out[(size_t)(m0 + quad * 4 + rr) * 256 + n0 + t * 16 + col] =
                f_to_bf16_bits(acc[t][rr]);
}

template <bool F32>
__device__ __forceinline__ void bias_body(KArgs& a, float* ws, int m, int tid) {
    __shared__ float bsh[256];
    float* beff = ws + OFF_BEFF;
    if (m < 3) {
        const void* bsrc = (m == 0) ? a.in[3] : (m == 1) ? a.in[5] : a.in[7];
        bsh[tid] = ld1f<F32>(bsrc, tid);
        __syncthreads();
        float acc = 0.f;
        size_t row = (size_t)(m * 256 + tid) * 256;
#pragma unroll 4
        for (int kc = 0; kc < 256; kc += 8) {
            bf16x8_t wr = ld8<F32>(a.in[8], row + kc);
#pragma unroll
            for (int t = 0; t < 8; ++t)
                acc += bsh[kc + t] * bf16_bits_to_f((ushort_t)wr[t]);
        }
        acc += ld1f<F32>(a.in[9], m * 256 + tid);
        beff[m * 256 + tid] = acc;
    } else {
        bsh[tid] = ld1f<F32>(a.in[11], tid);   // mha_ob
        __syncthreads();
        float acc = 0.f;
        for (int k = 0; k < 256; ++k)
            acc += bsh[k] * ld1f<F32>(a.in[12], (size_t)k * 256 + tid);  // Wo[k][j]
        acc += ld1f<F32>(a.in[13], tid);
        beff[3 * 256 + tid] = acc;
    }
}

__global__ __launch_bounds__(256) void k_fuse(KArgs a) {
    float* ws = a.ws;
    const int tid = threadIdx.x, bid = blockIdx.x;
    const int lane = tid & 63, wv = tid >> 6;
    const int col = lane & 15, quad = lane >> 4;
    int fl = detect_flag(a.in[0], tid);
    if (bid == 0 && tid == 0) *(int*)(ws + OFF_FLAG) = fl;

    if (bid < 16) {
        // batch ranges from sorted key_batch_idx (boundary detection)
        const int* kb = (const int*)a.in[17];
        int* kstart = (int*)(ws + OFF_KST);
        int* kend   = (int*)(ws + OFF_KEN);
        int j = bid * 256 + tid;
        if (j < NK) {
            int b = kb[j];
            if (j == 0) {
                for (int x = 0; x < b; ++x) { kstart[x] = 0; kend[x] = 0; }
                kstart[b] = 0;
            } else {
                int bp = kb[j - 1];
                if (bp != b) {
                    kend[bp] = j;
                    for (int x = bp + 1; x < b; ++x) { kstart[x] = j; kend[x] = j; }
                    kstart[b] = j;
                }
            }
            if (j == NK - 1) {
                kend[b] = NK;
                for (int x = b + 1; x < NB; ++x) { kstart[x] = NK; kend[x] = NK; }
            }
        }
    } else if (bid < 88) {
        int r = bid - 16;
        const void* A; const void* B; ushort_t* Out;
        size_t abase; int N, mb, nb, typ;
        if (r < 16)      { typ = 0; A = a.in[8]; abase = 0;      B = a.in[2]; Out = (ushort_t*)(ws + OFF_WQT); N = 256; mb = r >> 2; nb = r & 3; }
        else if (r < 36) { typ = 0; int rr = r - 16; A = a.in[8]; abase = 65536;  B = a.in[4]; Out = (ushort_t*)(ws + OFF_WKT); N = 320; mb = rr / 5; nb = rr % 5; }
        else if (r < 56) { typ = 0; int rr = r - 36; A = a.in[8]; abase = 131072; B = a.in[6]; Out = (ushort_t*)(ws + OFF_WVT); N = 320; mb = rr / 5; nb = rr % 5; }
        else             { typ = 1; int rr = r - 56; A = a.in[12]; abase = 0; B = a.in[10]; Out = (ushort_t*)(ws + OFF_WOT); N = 256; mb = rr >> 2; nb = rr & 3; }
        int m0 = mb * 64 + wv * 16, n0 = nb * 64;
        if (typ == 0) {
            if (fl) fuse_qkv_tile<false>(A, abase, B, Out, N, m0, n0, col, quad);
            else    fuse_qkv_tile<true >(A, abase, B, Out, N, m0, n0, col, quad);
        } else {
            if (fl) fuse_o_tile<false>(A, B, Out, m0, n0, col, quad);
            else    fuse_o_tile<true >(A, B, Out, m0, n0, col, quad);
        }
    } else {
        int m = bid - 88;
        if (fl) bias_body<false>(a, ws, m, tid);
        else    bias_body<true >(a, ws, m, tid);
    }
}

// ---------------------------------------------------------------------------
// K2: Q/K/V projections, 768 blocks. A = query/key nodes straight from d_in.
// ---------------------------------------------------------------------------
template <bool F32, int KK>
__device__ __forceinline__ void proj_body(const void* X, const ushort_t* WT,
                                          const float* bias, ushort_t* Z,
                                          int m0, int n0, int col, int quad) {
    f32x4_t acc[4];
#pragma unroll
    for (int t = 0; t < 4; ++t) acc[t] = (f32x4_t){0.f, 0.f, 0.f, 0.f};
    size_t aoff = (size_t)(m0 + col) * KK + quad * 8;
    const ushort_t* Wrow = WT + (size_t)(n0 + col) * KK + quad * 8;
#pragma unroll
    for (int kc = 0; kc < KK; kc += 32) {
        bf16x8_t af = ld8<F32>(X, aoff + kc);
#pragma unroll
        for (int t = 0; t < 4; ++t) {
            bf16x8_t bf = *(const bf16x8_t*)(Wrow + (size_t)t * 16 * KK + kc);
            acc[t] = __builtin_amdgcn_mfma_f32_16x16x32_bf16(af, bf, acc[t], 0, 0, 0);
        }
    }
#pragma unroll
    for (int t = 0; t < 4; ++t)
#pragma unroll
        for (int rr = 0; rr < 4; ++rr) {
            int n = n0 + t * 16 + col;
            Z[(size_t)(m0 + quad * 4 + rr) * 256 + n] =
                f_to_bf16_bits(acc[t][rr] + bias[n]);
        }
}

__global__ __launch_bounds__(256) void k_qkv(KArgs a) {
    float* ws = a.ws;
    const int tid = threadIdx.x, u = blockIdx.x;
    const int lane = tid & 63, wv = tid >> 6;
    const int col = lane & 15, quad = lane >> 4;
    const int fl = *(const int*)(ws + OFF_FLAG);
    const float* beff = ws + OFF_BEFF;

    if (u < 256) {
        int m0 = (u >> 2) * 64 + wv * 16, n0 = (u & 3) * 64;
        const ushort_t* WT = (const ushort_t*)(ws + OFF_WQT);
        ushort_t* Z = (ushort_t*)(ws + OFF_Q2B);
        if (fl) proj_body<false, 256>(a.in[0], WT, beff, Z, m0, n0, col, quad);
        else    proj_body<true , 256>(a.in[0], WT, beff, Z, m0, n0, col, quad);
    } else if (u < 512) {
        int uu = u - 256;
        int m0 = (uu >> 2) * 64 + wv * 16, n0 = (uu & 3) * 64;
        const ushort_t* WT = (const ushort_t*)(ws + OFF_WKT);
        ushort_t* Z = (ushort_t*)(ws + OFF_K2B);
        if (fl) proj_body<false, 320>(a.in[1], WT, beff + 256, Z, m0, n0, col, quad);
        else    proj_body<true , 320>(a.in[1], WT, beff + 256, Z, m0, n0, col, quad);
    } else {
        int uu = u - 512;
        int m0 = (uu >> 2) * 64 + wv * 16, n0 = (uu & 3) * 64;
        const ushort_t* WT = (const ushort_t*)(ws + OFF_WVT);
        ushort_t* Z = (ushort_t*)(ws + OFF_V2B);
        if (fl) proj_body<false, 320>(a.in[1], WT, beff + 512, Z, m0, n0, col, quad);
        else    proj_body<true , 320>(a.in[1], WT, beff + 512, Z, m0, n0, col, quad);
    }
}

// ---------------------------------------------------------------------------
// K3: MFMA flash attention (unchanged structure from round 5)
// ---------------------------------------------------------------------------
__global__ __launch_bounds__(256) void k_attn(KArgs a) {
    float* ws = a.ws;
    const ushort_t* q2b = (const ushort_t*)(ws + OFF_Q2B);
    const ushort_t* k2b = (const ushort_t*)(ws + OFF_K2B);
    const ushort_t* v2b = (const ushort_t*)(ws + OFF_V2B);
    const int* qb  = (const int*)a.in[16];
    const int* kst = (const int*)(ws + OFF_KST);
    const int* ken = (const int*)(ws + OFF_KEN);
    ushort_t* ctxb = (ushort_t*)(ws + OFF_CTXB);

    int wave = threadIdx.x >> 6;
    int lane = threadIdx.x & 63;
    int qt = blockIdx.x >> 1;
    int h  = ((blockIdx.x & 1) << 2) | wave;
    int q0 = qt * 16;
    int col  = lane & 15;
    int quad = lane >> 4;

    int qq = q0 + col;
    int bq_ = qb[qq];
    int j0q = kst[bq_], j1q = ken[bq_];
    int jlo = j0q, jhi = j1q;
#pragma unroll
    for (int off = 1; off < 16; off <<= 1) {
        jlo = min(jlo, __shfl_xor(jlo, off, 64));
        jhi = max(jhi, __shfl_xor(jhi, off, 64));
    }

    bf16x8_t qf = *(const bf16x8_t*)(q2b + (size_t)qq * HID + h * DH + quad * 8);

    f32x4_t accO = {0.f, 0.f, 0.f, 0.f};
    float m_st = -1e30f, l_st = 0.f;

    for (int kt = jlo; kt < jhi; kt += 16) {
        int krow = kt + col;
        if (krow > NK - 1) krow = NK - 1;
        bf16x8_t kf = *(const bf16x8_t*)(k2b + (size_t)krow * HID + h * DH + quad * 8);
        ushort_t vr[4];
#pragma unroll
        for (int j = 0; j < 4; ++j) {
            int vrow = kt + quad * 4 + j;
            if (vrow > NK - 1) vrow = NK - 1;
            vr[j] = v2b[(size_t)vrow * HID + h * DH + col];
        }
        f32x4_t S = __builtin_amdgcn_mfma_f32_16x16x32_bf16(
            kf, qf, (f32x4_t){0.f, 0.f, 0.f, 0.f}, 0, 0, 0);

        float s[4];
        float mt = -3e38f;
#pragma unroll
        for (int r = 0; r < 4; ++r) {
            int kk = kt + quad * 4 + r;
            bool ok = (kk >= j0q) && (kk < j1q);
            s[r] = ok ? S[r] * ATT_SCALE : -3e38f;
            mt = fmaxf(mt, s[r]);
        }
        mt = fmaxf(mt, __shfl_xor(mt, 16, 64));
        mt = fmaxf(mt, __shfl_xor(mt, 32, 64));
        float m_new = fmaxf(m_st, mt);
        float alpha = __expf(m_st - m_new);
        float p[4], ps = 0.f;
#pragma unroll
        for (int r = 0; r < 4; ++r) { p[r] = __expf(s[r] - m_new); ps += p[r]; }
        ps += __shfl_xor(ps, 16, 64);
        ps += __shfl_xor(ps, 32, 64);
        l_st = l_st * alpha + ps;
        m_st = m_new;

        bf16x4_t pb, vb;
#pragma unroll
        for (int r = 0; r < 4; ++r) {
            pb[r] = (short)f_to_bf16_bits(p[r]);
            vb[r] = (short)vr[r];
        }
#pragma unroll
        for (int r = 0; r < 4; ++r) {
            float aq = __shfl(alpha, quad * 4 + r, 64);
            accO[r] *= aq;
        }
        accO = __builtin_amdgcn_mfma_f32_16x16x16bf16_1k(pb, vb, accO, 0, 0, 0);
    }

#pragma unroll
    for (int r = 0; r < 4; ++r) {
        float lq = __shfl(l_st, quad * 4 + r, 64);
        float o = (lq > 0.f) ? accO[r] / lq : 0.f;
        int qrow = q0 + quad * 4 + r;
        ctxb[(size_t)qrow * HID + h * DH + col] = f_to_bf16_bits(o);
    }
}

// ---------------------------------------------------------------------------
// K4: O-projection + residual + LayerNorm fused. 64 blocks; each wave owns
// 16 full rows (acc[16] 16x16 tiles), LN via width-16 shuffles.
// ---------------------------------------------------------------------------
template <bool F32>
__device__ __forceinline__ void oln_body(KArgs& a, float* ws, int u,
                                         int wv, int col, int quad, int fl) {
    const ushort_t* ctxb = (const ushort_t*)(ws + OFF_CTXB);
    const ushort_t* wot  = (const ushort_t*)(ws + OFF_WOT);
    const float* beffO = ws + OFF_BEFF + 3 * 256;

    int m0 = u * 64 + wv * 16;
    f32x4_t acc[16];
#pragma unroll
    for (int t = 0; t < 16; ++t) acc[t] = (f32x4_t){0.f, 0.f, 0.f, 0.f};
    const ushort_t* Xrow = ctxb + (size_t)(m0 + col) * 256 + quad * 8;
    const ushort_t* Wbase = wot + (size_t)col * 256 + quad * 8;
#pragma unroll
    for (int kc = 0; kc < 256; kc += 32) {
        bf16x8_t af = *(const bf16x8_t*)(Xrow + kc);
#pragma unroll
        for (int t = 0; t < 16; ++t) {
            bf16x8_t bf = *(const bf16x8_t*)(Wbase + (size_t)t * 16 * 256 + kc);
            acc[t] = __builtin_amdgcn_mfma_f32_16x16x32_bf16(af, bf, acc[t], 0, 0, 0);
        }
    }
    float s_[4] = {0.f, 0.f, 0.f, 0.f};
    float ss_[4] = {0.f, 0.f, 0.f, 0.f};
#pragma unroll
    for (int t = 0; t < 16; ++t) {
        int n = t * 16 + col;
        float b = beffO[n];
#pragma unroll
        for (int rr = 0; rr < 4; ++rr) {
            int m = m0 + quad * 4 + rr;
            float x = acc[t][rr] + b + ld1f<F32>(a.in[0], (size_t)m * 256 + n);
            acc[t][rr] = x;
            s_[rr] += x;
            ss_[rr] += x * x;
        }
    }
#pragma unroll
    for (int off = 1; off < 16; off <<= 1) {
#pragma unroll
        for (int rr = 0; rr < 4; ++rr) {
            s_[rr]  += __shfl_xor(s_[rr],  off, 16);
            ss_[rr] += __shfl_xor(ss_[rr], off, 16);
        }
    }
    float mu[4], inv[4];
#pragma unroll
    for (int rr = 0; rr < 4; ++rr) {
        mu[rr] = s_[rr] * (1.f / QD);
        float var = ss_[rr] * (1.f / QD) - mu[rr] * mu[rr];
        inv[rr] = rsqrtf(var + LN_EPS);
    }
#pragma unroll
    for (int t = 0; t < 16; ++t) {
        int n = t * 16 + col;
        float g = ld1f<F32>(a.in[14], n), bb = ld1f<F32>(a.in[15], n);
#pragma unroll
        for (int rr = 0; rr < 4; ++rr) {
            int m = m0 + quad * 4 + rr;
            float y = (acc[t][rr] - mu[rr]) * inv[rr] * g + bb;
            size_t idx = (size_t)m * 256 + n;
            if (fl) ((ushort_t*)a.out)[idx] = f_to_bf16_bits(y);
            else    ((float*)a.out)[idx] = y;
        }
    }
}

__global__ __launch_bounds__(256) void k_oln(KArgs a) {
    float* ws = a.ws;
    const int tid = threadIdx.x;
    const int lane = tid & 63, wv = tid >> 6;
    const int col = lane & 15, quad = lane >> 4;
    const int fl = *(const int*)(ws + OFF_FLAG);
    if (fl) oln_body<false>(a, ws, blockIdx.x, wv, col, quad, fl);
    else    oln_body<true >(a, ws, blockIdx.x, wv, col, quad, fl);
}

extern "C" void kernel_launch(void* const* d_in, const int* in_sizes, int n_in,
                              void* d_out, int out_size, void* d_ws, size_t ws_size,
                              hipStream_t stream) {
    KArgs a;
    for (int i = 0; i < 18; ++i) a.in[i] = d_in[i];
    a.ws = (float*)d_ws;
    a.out = d_out;

    k_fuse<<<92, 256, 0, stream>>>(a);
    k_qkv<<<768, 256, 0, stream>>>(a);
    k_attn<<<512, 256, 0, stream>>>(a);
    k_oln<<<64, 256, 0, stream>>>(a);
}